// Round 1
// baseline (522.596 us; speedup 1.0000x reference)
//
#include <hip/hip_runtime.h>

#define B_  2
#define N_  65536
#define C_  192
#define NH_ 4
#define HD_ 48
#define GS_ 128
#define NG_ 512
#define NTILES_ 256   // per batch, tile = 256 tokens

__device__ __forceinline__ unsigned short f2bf(float f) {
    unsigned u = __float_as_uint(f);
    unsigned r = (u + 0x7FFFu + ((u >> 16) & 1u)) >> 16;
    return (unsigned short)r;
}
__device__ __forceinline__ float bf2f(unsigned short s) {
    return __uint_as_float(((unsigned)s) << 16);
}

// ---------------- K1: per-token argmax over 64 sim categories ----------------
__global__ __launch_bounds__(256) void argmax_kernel(const float* __restrict__ sim,
                                                     int* __restrict__ keys) {
    int lane  = threadIdx.x & 63;
    int token = blockIdx.x * 4 + (threadIdx.x >> 6);
    float v = sim[(size_t)token * 64 + lane];
    int idx = lane;
    #pragma unroll
    for (int m = 1; m < 64; m <<= 1) {
        float ov = __shfl_xor(v, m);
        int   oi = __shfl_xor(idx, m);
        if (ov > v || (ov == v && oi < idx)) { v = ov; idx = oi; }
    }
    if (lane == 0) keys[token] = idx;
}

// ---------------- K2: per-tile histogram (tile = 256 tokens) ----------------
__global__ __launch_bounds__(256) void hist_kernel(const int* __restrict__ keys,
                                                   int* __restrict__ counts) {
    __shared__ int hcnt[64];
    int tid  = threadIdx.x;
    int tile = blockIdx.x & (NTILES_ - 1);
    int bz   = blockIdx.x >> 8;
    if (tid < 64) hcnt[tid] = 0;
    __syncthreads();
    int k = keys[bz * N_ + tile * 256 + tid];
    atomicAdd(&hcnt[k], 1);
    __syncthreads();
    if (tid < 64) counts[(bz * NTILES_ + tile) * 64 + tid] = hcnt[tid];
}

// ---------------- K3: scan tiles per key, then exclusive key-base scan -------
__global__ __launch_bounds__(64) void scan_kernel(int* __restrict__ counts) {
    int bz = blockIdx.x;
    int k  = threadIdx.x; // 0..63
    int run = 0;
    for (int t = 0; t < NTILES_; ++t) {
        int idx = (bz * NTILES_ + t) * 64 + k;
        int c = counts[idx];
        counts[idx] = run;       // exclusive within key
        run += c;
    }
    int total = run;
    int incl = run;
    #pragma unroll
    for (int off = 1; off < 64; off <<= 1) {
        int v = __shfl_up(incl, off);
        if (k >= off) incl += v;
    }
    int base = incl - total;     // exclusive prefix over keys
    for (int t = 0; t < NTILES_; ++t)
        counts[(bz * NTILES_ + t) * 64 + k] += base;
}

// ---------------- K4: stable in-tile rank + scatter --------------------------
__global__ __launch_bounds__(256) void rank_kernel(const int* __restrict__ keys,
                                                   const int* __restrict__ counts,
                                                   int* __restrict__ sidx,
                                                   int* __restrict__ dest) {
    __shared__ int lk[256];
    int tid  = threadIdx.x;
    int tile = blockIdx.x & (NTILES_ - 1);
    int bz   = blockIdx.x >> 8;
    int tok  = tile * 256 + tid;
    int key  = keys[bz * N_ + tok];
    lk[tid]  = key;
    __syncthreads();
    int c = 0;
    for (int j = 0; j < tid; ++j) c += (lk[j] == key) ? 1 : 0;
    int pos = counts[(bz * NTILES_ + tile) * 64 + key] + c;
    sidx[bz * N_ + pos] = tok;
    dest[bz * N_ + tok] = pos;
}

// ---------------- K5: grouped attention, one block per (b, group, head) ------
// fp32 QK^T + softmax (precision-critical: logits ~ N(0, 69^2)),
// P stored bf16 in LDS (reuses K region), fp32 PV, bf16 output staging.
__global__ __launch_bounds__(256) void attn_kernel(const float* __restrict__ qkv,
                                                   const float* __restrict__ lscale,
                                                   const int* __restrict__ sort_idx,
                                                   unsigned short* __restrict__ oattn) {
    int x  = blockIdx.x;
    int h  = x & 3;
    int g  = (x >> 2) & (NG_ - 1);
    int bz = x >> 11;

    __shared__ union KP {
        float k[GS_][HD_];                 // 24576 B
        unsigned short p[GS_][130];        // 33280 B (pad 130: 4-way max on PV reads)
    } uKP;
    __shared__ float vbuf[GS_][HD_];       // 24576 B
    __shared__ int   sidx_s[GS_];
    __shared__ float pmax[GS_][4];
    __shared__ float psum[GS_][4];

    int tid = threadIdx.x;
    if (tid < GS_) sidx_s[tid] = sort_idx[bz * N_ + g * GS_ + tid];
    __syncthreads();

    // --- load K, V into LDS (2 threads per token: one K slice, one V slice) ---
    {
        int i = tid >> 1, part = tid & 1;
        int src = sidx_s[i];
        const float4* rp = (const float4*)(qkv + (size_t)(bz * N_ + src) * 576
                                           + (part ? 384 : 192) + h * HD_);
        float4* dst = (float4*)(part ? &vbuf[i][0] : &uKP.k[i][0]);
        #pragma unroll
        for (int c = 0; c < 12; ++c) dst[c] = rp[c];
    }

    // --- each thread owns 2 query rows, 1/4 of the keys ---
    int p  = tid & 63;
    int q  = tid >> 6;
    int r0 = 2 * p, r1 = r0 + 1;

    float qra[HD_], qrb[HD_];
    {
        int s0 = sidx_s[r0], s1 = sidx_s[r1];
        const float* a = qkv + (size_t)(bz * N_ + s0) * 576 + h * HD_;
        const float* b = qkv + (size_t)(bz * N_ + s1) * 576 + h * HD_;
        #pragma unroll
        for (int d = 0; d < HD_; ++d) { qra[d] = a[d]; qrb[d] = b[d]; }
    }
    float scale = __expf(fminf(lscale[0], __logf(100.0f)));
    __syncthreads();

    // --- S = scale * Q K^T  (each thread: 2 rows x 32 keys) ---
    float sa[32], sb[32];
    #pragma unroll
    for (int j = 0; j < 32; ++j) {
        int key = q * 32 + j;
        const float* krow = &uKP.k[key][0];
        float accA = 0.f, accB = 0.f;
        #pragma unroll
        for (int d = 0; d < HD_; ++d) {
            float kv = krow[d];
            accA = fmaf(qra[d], kv, accA);
            accB = fmaf(qrb[d], kv, accB);
        }
        sa[j] = accA * scale;
        sb[j] = accB * scale;
    }

    // --- softmax (cross-quarter combine via LDS) ---
    float ma = -1e30f, mb = -1e30f;
    #pragma unroll
    for (int j = 0; j < 32; ++j) { ma = fmaxf(ma, sa[j]); mb = fmaxf(mb, sb[j]); }
    pmax[r0][q] = ma; pmax[r1][q] = mb;
    __syncthreads();
    float gma = fmaxf(fmaxf(pmax[r0][0], pmax[r0][1]), fmaxf(pmax[r0][2], pmax[r0][3]));
    float gmb = fmaxf(fmaxf(pmax[r1][0], pmax[r1][1]), fmaxf(pmax[r1][2], pmax[r1][3]));
    float ea = 0.f, eb = 0.f;
    #pragma unroll
    for (int j = 0; j < 32; ++j) {
        sa[j] = __expf(sa[j] - gma); ea += sa[j];
        sb[j] = __expf(sb[j] - gmb); eb += sb[j];
    }
    psum[r0][q] = ea; psum[r1][q] = eb;
    __syncthreads();
    float ga = psum[r0][0] + psum[r0][1] + psum[r0][2] + psum[r0][3];
    float gb = psum[r1][0] + psum[r1][1] + psum[r1][2] + psum[r1][3];

    // --- write P (bf16) over the K region; K reads all completed before pmax sync ---
    #pragma unroll
    for (int j = 0; j < 32; ++j) {
        uKP.p[r0][q * 32 + j] = f2bf(sa[j]);
        uKP.p[r1][q * 32 + j] = f2bf(sb[j]);
    }
    __syncthreads();

    // --- O = P V  (each thread: 2 rows x 12 dims) ---
    float oa[12], ob[12];
    #pragma unroll
    for (int d = 0; d < 12; ++d) { oa[d] = 0.f; ob[d] = 0.f; }
    #pragma unroll 2
    for (int key = 0; key < GS_; ++key) {
        float pa = bf2f(uKP.p[r0][key]);
        float pb = bf2f(uKP.p[r1][key]);
        const float* vrow = &vbuf[key][q * 12];
        #pragma unroll
        for (int d = 0; d < 12; ++d) {
            float vv = vrow[d];
            oa[d] = fmaf(pa, vv, oa[d]);
            ob[d] = fmaf(pb, vv, ob[d]);
        }
    }
    float ia = 1.0f / ga, ib = 1.0f / gb;
    size_t base0 = ((size_t)(bz * N_ + g * GS_ + r0)) * C_ + h * HD_ + q * 12;
    size_t base1 = ((size_t)(bz * N_ + g * GS_ + r1)) * C_ + h * HD_ + q * 12;
    #pragma unroll
    for (int d = 0; d < 12; ++d) {
        oattn[base0 + d] = f2bf(oa[d] * ia);
        oattn[base1 + d] = f2bf(ob[d] * ib);
    }
}

// ---------------- K6: unshuffle + x @ W^T + b --------------------------------
// block: 64 gathered rows x 96 cols; bf16 LDS tiles, stride 194 (97 dwords -> 
// bank stride 1 mod 32, conflict-free); fp32 accumulate.
__global__ __launch_bounds__(256) void proj_kernel(const unsigned short* __restrict__ oattn,
                                                   const int* __restrict__ dest,
                                                   const float* __restrict__ W,
                                                   const float* __restrict__ bias,
                                                   float* __restrict__ out) {
    __shared__ unsigned short wt[96][194];
    __shared__ unsigned short it[64][194];
    __shared__ int mpos[64];

    int tid   = threadIdx.x;
    int jbase = blockIdx.y * 96;
    int m0    = blockIdx.x * 64;

    if (tid < 64) {
        int m = m0 + tid;
        int bz = m >> 16;
        mpos[tid] = bz * N_ + dest[m];   // dest flat index == m (bz*N + t)
    }
    // W tile (96 x 192), fp32 -> bf16
    for (int idx = tid; idx < 96 * 48; idx += 256) {
        int row = idx / 48, c4 = idx - row * 48;
        float4 wv = ((const float4*)(W + (size_t)(jbase + row) * C_))[c4];
        unsigned* wrow = (unsigned*)&wt[row][0];
        wrow[c4 * 2]     = (unsigned)f2bf(wv.x) | ((unsigned)f2bf(wv.y) << 16);
        wrow[c4 * 2 + 1] = (unsigned)f2bf(wv.z) | ((unsigned)f2bf(wv.w) << 16);
    }
    __syncthreads();
    // gathered input rows (64 x 192 bf16 = 24 uint4 per row)
    for (int idx = tid; idx < 64 * 24; idx += 256) {
        int row = idx / 24, c = idx - row * 24;
        uint4 v = ((const uint4*)(oattn + (size_t)mpos[row] * C_))[c];
        unsigned* irow = (unsigned*)&it[row][0];
        irow[c * 4 + 0] = v.x; irow[c * 4 + 1] = v.y;
        irow[c * 4 + 2] = v.z; irow[c * 4 + 3] = v.w;
    }
    __syncthreads();

    int tc = tid & 15, tr = tid >> 4;
    float acc[4][6];
    #pragma unroll
    for (int rr = 0; rr < 4; ++rr)
        #pragma unroll
        for (int cc = 0; cc < 6; ++cc) acc[rr][cc] = 0.f;

    const unsigned* itU = (const unsigned*)&it[0][0];
    const unsigned* wtU = (const unsigned*)&wt[0][0];
    #pragma unroll 2
    for (int kk = 0; kk < 96; ++kk) {
        float alo[4], ahi[4];
        #pragma unroll
        for (int rr = 0; rr < 4; ++rr) {
            unsigned a = itU[(size_t)(rr * 16 + tr) * 97 + kk];
            alo[rr] = __uint_as_float(a << 16);
            ahi[rr] = __uint_as_float(a & 0xFFFF0000u);
        }
        #pragma unroll
        for (int cc = 0; cc < 6; ++cc) {
            unsigned w = wtU[(size_t)(cc * 16 + tc) * 97 + kk];
            float wlo = __uint_as_float(w << 16);
            float whi = __uint_as_float(w & 0xFFFF0000u);
            #pragma unroll
            for (int rr = 0; rr < 4; ++rr) {
                acc[rr][cc] = fmaf(alo[rr], wlo, acc[rr][cc]);
                acc[rr][cc] = fmaf(ahi[rr], whi, acc[rr][cc]);
            }
        }
    }
    #pragma unroll
    for (int cc = 0; cc < 6; ++cc) {
        int j = jbase + cc * 16 + tc;
        float bj = bias[j];
        #pragma unroll
        for (int rr = 0; rr < 4; ++rr) {
            int m = m0 + rr * 16 + tr;
            out[(size_t)m * C_ + j] = acc[rr][cc] + bj;
        }
    }
}

extern "C" void kernel_launch(void* const* d_in, const int* in_sizes, int n_in,
                              void* d_out, int out_size, void* d_ws, size_t ws_size,
                              hipStream_t stream) {
    const float* qkv    = (const float*)d_in[0];
    const float* sim    = (const float*)d_in[1];
    const float* proj_w = (const float*)d_in[2];
    const float* proj_b = (const float*)d_in[3];
    const float* lscale = (const float*)d_in[4];
    float* out = (float*)d_out;

    char* ws = (char*)d_ws;
    int* keys   = (int*)(ws);                         // B*N*4      = 524288
    int* dest   = (int*)(ws + 524288);                // B*N*4
    int* sidx   = (int*)(ws + 1048576);               // B*N*4
    int* counts = (int*)(ws + 1572864);               // B*256*64*4 = 131072
    unsigned short* oattn = (unsigned short*)(ws + 1703936); // B*N*192*2 = 50331648

    argmax_kernel<<<32768, 256, 0, stream>>>(sim, keys);
    hist_kernel<<<B_ * NTILES_, 256, 0, stream>>>(keys, counts);
    scan_kernel<<<B_, 64, 0, stream>>>(counts);
    rank_kernel<<<B_ * NTILES_, 256, 0, stream>>>(keys, counts, sidx, dest);
    attn_kernel<<<B_ * NG_ * NH_, 256, 0, stream>>>(qkv, lscale, sidx, oattn);
    proj_kernel<<<dim3((B_ * N_) / 64, 2), 256, 0, stream>>>(oattn, dest, proj_w, proj_b, out);
}

// Round 2
// 358.696 us; speedup vs baseline: 1.4569x; 1.4569x over previous
//
#include <hip/hip_runtime.h>

#define B_  2
#define N_  65536
#define C_  192
#define NH_ 4
#define HD_ 48
#define GS_ 128
#define NG_ 512
#define NTILES_ 256   // per batch, tile = 256 tokens

typedef __attribute__((ext_vector_type(8))) short short8;
typedef __attribute__((ext_vector_type(4))) float f32x4;

__device__ __forceinline__ unsigned short f2bf(float f) {
    unsigned u = __float_as_uint(f);
    unsigned r = (u + 0x7FFFu + ((u >> 16) & 1u)) >> 16;
    return (unsigned short)r;
}
__device__ __forceinline__ float bf2f(unsigned short s) {
    return __uint_as_float(((unsigned)s) << 16);
}

// ---------------- K1: per-token argmax over 64 sim categories ----------------
__global__ __launch_bounds__(256) void argmax_kernel(const float* __restrict__ sim,
                                                     int* __restrict__ keys) {
    int lane  = threadIdx.x & 63;
    int token = blockIdx.x * 4 + (threadIdx.x >> 6);
    float v = sim[(size_t)token * 64 + lane];
    int idx = lane;
    #pragma unroll
    for (int m = 1; m < 64; m <<= 1) {
        float ov = __shfl_xor(v, m);
        int   oi = __shfl_xor(idx, m);
        if (ov > v || (ov == v && oi < idx)) { v = ov; idx = oi; }
    }
    if (lane == 0) keys[token] = idx;
}

// ---------------- K2: per-tile histogram (tile = 256 tokens) ----------------
__global__ __launch_bounds__(256) void hist_kernel(const int* __restrict__ keys,
                                                   int* __restrict__ counts) {
    __shared__ int hcnt[64];
    int tid  = threadIdx.x;
    int tile = blockIdx.x & (NTILES_ - 1);
    int bz   = blockIdx.x >> 8;
    if (tid < 64) hcnt[tid] = 0;
    __syncthreads();
    int k = keys[bz * N_ + tile * 256 + tid];
    atomicAdd(&hcnt[k], 1);
    __syncthreads();
    if (tid < 64) counts[(bz * NTILES_ + tile) * 64 + tid] = hcnt[tid];
}

// ---------------- K3: two-level scan, 256 threads (64 keys x 4 quarters) -----
__global__ __launch_bounds__(256) void scan_kernel(int* __restrict__ counts) {
    __shared__ int qsum[4][64];
    __shared__ int kbase[64];
    int bz = blockIdx.x;
    int k  = threadIdx.x & 63;
    int qt = threadIdx.x >> 6;
    int base_idx = (bz * NTILES_) * 64 + k;

    int sum = 0;
    #pragma unroll 8
    for (int t = qt * 64; t < qt * 64 + 64; ++t) sum += counts[base_idx + t * 64];
    qsum[qt][k] = sum;
    __syncthreads();

    if (qt == 0) {
        int tot = qsum[0][k] + qsum[1][k] + qsum[2][k] + qsum[3][k];
        int incl = tot;
        #pragma unroll
        for (int off = 1; off < 64; off <<= 1) {
            int v = __shfl_up(incl, off);
            if (k >= off) incl += v;
        }
        kbase[k] = incl - tot;   // exclusive prefix over keys
    }
    __syncthreads();

    int run = kbase[k];
    for (int q2 = 0; q2 < qt; ++q2) run += qsum[q2][k];
    #pragma unroll 8
    for (int t = qt * 64; t < qt * 64 + 64; ++t) {
        int idx = base_idx + t * 64;
        int c = counts[idx];
        counts[idx] = run;
        run += c;
    }
}

// ---------------- K4: stable in-tile rank via match-any ballot ---------------
__global__ __launch_bounds__(256) void rank_kernel(const int* __restrict__ keys,
                                                   const int* __restrict__ counts,
                                                   int* __restrict__ sidx,
                                                   int* __restrict__ dest) {
    __shared__ int whist[4 * 64];
    int tid  = threadIdx.x;
    int tile = blockIdx.x & (NTILES_ - 1);
    int bz   = blockIdx.x >> 8;
    whist[tid] = 0;
    __syncthreads();

    int tok = tile * 256 + tid;
    int key = keys[bz * N_ + tok];
    int w = tid >> 6, lane = tid & 63;

    unsigned long long mask = ~0ull;
    #pragma unroll
    for (int b = 0; b < 6; ++b) {
        unsigned long long bb = __ballot((key >> b) & 1);
        mask &= ((key >> b) & 1) ? bb : ~bb;
    }
    unsigned long long lt = (lane == 0) ? 0ull : (~0ull >> (64 - lane));
    int rank = __popcll(mask & lt);
    if (rank == 0) whist[w * 64 + key] = __popcll(mask);
    __syncthreads();

    int base = counts[(bz * NTILES_ + tile) * 64 + key];
    for (int w2 = 0; w2 < w; ++w2) base += whist[w2 * 64 + key];
    int pos = base + rank;
    sidx[bz * N_ + pos] = tok;
    dest[bz * N_ + tok] = pos;
}

// ---------------- K5: MFMA grouped attention, one block per (b, group, head) -
// Split-bf16 QK^T: S = Qh*Kh + Qh*Kl + Ql*Kh via concat-144 K-dim
// [Qh|Qh|Ql] x [Kh|Kl|Kh], 5 k-steps of 16x16x32 (last step zero-padded in
// registers). fp32 softmax in C-layout registers. P bf16 -> LDS (over K'),
// PV via bf16 MFMA with transposed V tile.
__global__ __launch_bounds__(256) void attn_kernel(const float* __restrict__ qkv,
                                                   const float* __restrict__ lscale,
                                                   const int* __restrict__ sort_idx,
                                                   unsigned short* __restrict__ oattn) {
    __shared__ unsigned short kp[128 * 152];   // K' [128][152]; later P [128][136]
    __shared__ unsigned short vt[48 * 136];    // V transposed [48][136]
    __shared__ int sidx_s[128];

    int x  = blockIdx.x;
    int h  = x & 3;
    int g  = (x >> 2) & (NG_ - 1);
    int bz = x >> 11;
    int tid = threadIdx.x;

    if (tid < 128) sidx_s[tid] = sort_idx[bz * N_ + g * GS_ + tid];
    __syncthreads();

    // ---- stage K' (hi|lo|hi concat) and Vt (transposed bf16) ----
    {
        int i = tid >> 1, part = tid & 1;
        size_t rb = (size_t)(bz * N_ + sidx_s[i]) * 576 + (part ? 384 : 192) + h * 48;
        const float4* src = (const float4*)(qkv + rb);
        if (part == 0) {
            unsigned hp[24], lp[24];
            #pragma unroll
            for (int m = 0; m < 12; ++m) {
                float4 f = src[m];
                float fv[4] = {f.x, f.y, f.z, f.w};
                #pragma unroll
                for (int j2 = 0; j2 < 2; ++j2) {
                    unsigned short h0 = f2bf(fv[2 * j2]);
                    unsigned short h1 = f2bf(fv[2 * j2 + 1]);
                    unsigned short l0 = f2bf(fv[2 * j2] - bf2f(h0));
                    unsigned short l1 = f2bf(fv[2 * j2 + 1] - bf2f(h1));
                    hp[m * 2 + j2] = (unsigned)h0 | ((unsigned)h1 << 16);
                    lp[m * 2 + j2] = (unsigned)l0 | ((unsigned)l1 << 16);
                }
            }
            uint4* kw = (uint4*)(kp + (size_t)i * 152);
            #pragma unroll
            for (int m = 0; m < 6; ++m) {
                kw[m]      = make_uint4(hp[4*m], hp[4*m+1], hp[4*m+2], hp[4*m+3]); // Kh @ 0
                kw[m + 6]  = make_uint4(lp[4*m], lp[4*m+1], lp[4*m+2], lp[4*m+3]); // Kl @ 48
                kw[m + 12] = make_uint4(hp[4*m], hp[4*m+1], hp[4*m+2], hp[4*m+3]); // Kh @ 96
            }
        } else {
            #pragma unroll
            for (int m = 0; m < 12; ++m) {
                float4 f = src[m];
                vt[(m * 4 + 0) * 136 + i] = f2bf(f.x);
                vt[(m * 4 + 1) * 136 + i] = f2bf(f.y);
                vt[(m * 4 + 2) * 136 + i] = f2bf(f.z);
                vt[(m * 4 + 3) * 136 + i] = f2bf(f.w);
            }
        }
    }

    float scale = __expf(fminf(lscale[0], 4.60517019f));
    int lane = tid & 63, wid = tid >> 6;
    int lr = lane & 15, lg = lane >> 4;
    int qt0 = wid * 2, qt1 = wid * 2 + 1;
    size_t qg0 = (size_t)(bz * N_ + sidx_s[qt0 * 16 + lr]) * 576 + h * 48;
    size_t qg1 = (size_t)(bz * N_ + sidx_s[qt1 * 16 + lr]) * 576 + h * 48;
    __syncthreads();

    // ---- QK^T ----
    f32x4 acc0[8], acc1[8];
    #pragma unroll
    for (int kt = 0; kt < 8; ++kt) { acc0[kt] = (f32x4)0.f; acc1[kt] = (f32x4)0.f; }

    int chunk = lg;  // chunk = s*4 + lg
    #pragma unroll
    for (int s = 0; s < 5; ++s, chunk += 4) {
        short8 a0 = (short8)0, a1 = (short8)0;
        if (chunk < 18) {
            int sec  = chunk / 6;               // 0,1 -> hi ; 2 -> lo
            int dim8 = (chunk - sec * 6) * 8;
            const float4* p0 = (const float4*)(qkv + qg0 + dim8);
            const float4* p1 = (const float4*)(qkv + qg1 + dim8);
            float4 f0a = p0[0], f0b = p0[1], f1a = p1[0], f1b = p1[1];
            float fv0[8] = {f0a.x, f0a.y, f0a.z, f0a.w, f0b.x, f0b.y, f0b.z, f0b.w};
            float fv1[8] = {f1a.x, f1a.y, f1a.z, f1a.w, f1b.x, f1b.y, f1b.z, f1b.w};
            #pragma unroll
            for (int j = 0; j < 8; ++j) {
                unsigned short h0 = f2bf(fv0[j]);
                unsigned short h1 = f2bf(fv1[j]);
                a0[j] = (sec == 2) ? (short)f2bf(fv0[j] - bf2f(h0)) : (short)h0;
                a1[j] = (sec == 2) ? (short)f2bf(fv1[j] - bf2f(h1)) : (short)h1;
            }
        }
        #pragma unroll
        for (int kt = 0; kt < 8; ++kt) {
            short8 b = (short8)0;
            if (chunk < 18)
                b = *(const short8*)(kp + (size_t)(kt * 16 + lr) * 152 + chunk * 8);
            acc0[kt] = __builtin_amdgcn_mfma_f32_16x16x32_bf16(a0, b, acc0[kt], 0, 0, 0);
            acc1[kt] = __builtin_amdgcn_mfma_f32_16x16x32_bf16(a1, b, acc1[kt], 0, 0, 0);
        }
    }

    // ---- softmax (rows = lg*4+r, cols = kt*16+lr) ----
    float inv0[4], inv1[4];
    {
        float mx0[4], mx1[4];
        #pragma unroll
        for (int r = 0; r < 4; ++r) { mx0[r] = -1e30f; mx1[r] = -1e30f; }
        #pragma unroll
        for (int kt = 0; kt < 8; ++kt)
            #pragma unroll
            for (int r = 0; r < 4; ++r) {
                acc0[kt][r] *= scale; acc1[kt][r] *= scale;
                mx0[r] = fmaxf(mx0[r], acc0[kt][r]);
                mx1[r] = fmaxf(mx1[r], acc1[kt][r]);
            }
        #pragma unroll
        for (int m = 1; m < 16; m <<= 1)
            #pragma unroll
            for (int r = 0; r < 4; ++r) {
                mx0[r] = fmaxf(mx0[r], __shfl_xor(mx0[r], m));
                mx1[r] = fmaxf(mx1[r], __shfl_xor(mx1[r], m));
            }
        float sm0[4] = {0.f, 0.f, 0.f, 0.f}, sm1[4] = {0.f, 0.f, 0.f, 0.f};
        #pragma unroll
        for (int kt = 0; kt < 8; ++kt)
            #pragma unroll
            for (int r = 0; r < 4; ++r) {
                float e0 = __expf(acc0[kt][r] - mx0[r]);
                float e1 = __expf(acc1[kt][r] - mx1[r]);
                acc0[kt][r] = e0; acc1[kt][r] = e1;
                sm0[r] += e0; sm1[r] += e1;
            }
        #pragma unroll
        for (int m = 1; m < 16; m <<= 1)
            #pragma unroll
            for (int r = 0; r < 4; ++r) {
                sm0[r] += __shfl_xor(sm0[r], m);
                sm1[r] += __shfl_xor(sm1[r], m);
            }
        #pragma unroll
        for (int r = 0; r < 4; ++r) { inv0[r] = 1.f / sm0[r]; inv1[r] = 1.f / sm1[r]; }
    }

    __syncthreads();   // all K' reads complete before P overwrites it

    // ---- write P (bf16, unnormalized) over K' region ----
    #pragma unroll
    for (int kt = 0; kt < 8; ++kt)
        #pragma unroll
        for (int r = 0; r < 4; ++r) {
            kp[(size_t)(qt0 * 16 + lg * 4 + r) * 136 + kt * 16 + lr] = f2bf(acc0[kt][r]);
            kp[(size_t)(qt1 * 16 + lg * 4 + r) * 136 + kt * 16 + lr] = f2bf(acc1[kt][r]);
        }
    __syncthreads();

    // ---- PV ----
    f32x4 o0[3], o1[3];
    #pragma unroll
    for (int dt = 0; dt < 3; ++dt) { o0[dt] = (f32x4)0.f; o1[dt] = (f32x4)0.f; }
    #pragma unroll
    for (int ks = 0; ks < 4; ++ks) {
        short8 a0 = *(const short8*)(kp + (size_t)(qt0 * 16 + lr) * 136 + ks * 32 + lg * 8);
        short8 a1 = *(const short8*)(kp + (size_t)(qt1 * 16 + lr) * 136 + ks * 32 + lg * 8);
        #pragma unroll
        for (int dt = 0; dt < 3; ++dt) {
            short8 bv = *(const short8*)(vt + (size_t)(dt * 16 + lr) * 136 + ks * 32 + lg * 8);
            o0[dt] = __builtin_amdgcn_mfma_f32_16x16x32_bf16(a0, bv, o0[dt], 0, 0, 0);
            o1[dt] = __builtin_amdgcn_mfma_f32_16x16x32_bf16(a1, bv, o1[dt], 0, 0, 0);
        }
    }

    // ---- store (normalize by row sums) ----
    #pragma unroll
    for (int dt = 0; dt < 3; ++dt)
        #pragma unroll
        for (int r = 0; r < 4; ++r) {
            int row0 = qt0 * 16 + lg * 4 + r;
            int row1 = qt1 * 16 + lg * 4 + r;
            oattn[(size_t)(bz * N_ + g * GS_ + row0) * C_ + h * HD_ + dt * 16 + lr] =
                f2bf(o0[dt][r] * inv0[r]);
            oattn[(size_t)(bz * N_ + g * GS_ + row1) * C_ + h * HD_ + dt * 16 + lr] =
                f2bf(o1[dt][r] * inv1[r]);
        }
}

// ---------------- K6: unshuffle + x @ W^T + b --------------------------------
__global__ __launch_bounds__(256) void proj_kernel(const unsigned short* __restrict__ oattn,
                                                   const int* __restrict__ dest,
                                                   const float* __restrict__ W,
                                                   const float* __restrict__ bias,
                                                   float* __restrict__ out) {
    __shared__ unsigned short wt[96][194];
    __shared__ unsigned short it[64][194];
    __shared__ int mpos[64];

    int tid   = threadIdx.x;
    int jbase = blockIdx.y * 96;
    int m0    = blockIdx.x * 64;

    if (tid < 64) {
        int m = m0 + tid;
        int bz = m >> 16;
        mpos[tid] = bz * N_ + dest[m];
    }
    for (int idx = tid; idx < 96 * 48; idx += 256) {
        int row = idx / 48, c4 = idx - row * 48;
        float4 wv = ((const float4*)(W + (size_t)(jbase + row) * C_))[c4];
        unsigned* wrow = (unsigned*)&wt[row][0];
        wrow[c4 * 2]     = (unsigned)f2bf(wv.x) | ((unsigned)f2bf(wv.y) << 16);
        wrow[c4 * 2 + 1] = (unsigned)f2bf(wv.z) | ((unsigned)f2bf(wv.w) << 16);
    }
    __syncthreads();
    for (int idx = tid; idx < 64 * 24; idx += 256) {
        int row = idx / 24, c = idx - row * 24;
        uint4 v = ((const uint4*)(oattn + (size_t)mpos[row] * C_))[c];
        unsigned* irow = (unsigned*)&it[row][0];
        irow[c * 4 + 0] = v.x; irow[c * 4 + 1] = v.y;
        irow[c * 4 + 2] = v.z; irow[c * 4 + 3] = v.w;
    }
    __syncthreads();

    int tc = tid & 15, tr = tid >> 4;
    float acc[4][6];
    #pragma unroll
    for (int rr = 0; rr < 4; ++rr)
        #pragma unroll
        for (int cc = 0; cc < 6; ++cc) acc[rr][cc] = 0.f;

    const unsigned* itU = (const unsigned*)&it[0][0];
    const unsigned* wtU = (const unsigned*)&wt[0][0];
    #pragma unroll 2
    for (int kk = 0; kk < 96; ++kk) {
        float alo[4], ahi[4];
        #pragma unroll
        for (int rr = 0; rr < 4; ++rr) {
            unsigned a = itU[(size_t)(rr * 16 + tr) * 97 + kk];
            alo[rr] = __uint_as_float(a << 16);
            ahi[rr] = __uint_as_float(a & 0xFFFF0000u);
        }
        #pragma unroll
        for (int cc = 0; cc < 6; ++cc) {
            unsigned w = wtU[(size_t)(cc * 16 + tc) * 97 + kk];
            float wlo = __uint_as_float(w << 16);
            float whi = __uint_as_float(w & 0xFFFF0000u);
            #pragma unroll
            for (int rr = 0; rr < 4; ++rr) {
                acc[rr][cc] = fmaf(alo[rr], wlo, acc[rr][cc]);
                acc[rr][cc] = fmaf(ahi[rr], whi, acc[rr][cc]);
            }
        }
    }
    #pragma unroll
    for (int cc = 0; cc < 6; ++cc) {
        int j = jbase + cc * 16 + tc;
        float bj = bias[j];
        #pragma unroll
        for (int rr = 0; rr < 4; ++rr) {
            int m = m0 + rr * 16 + tr;
            out[(size_t)m * C_ + j] = acc[rr][cc] + bj;
        }
    }
}

extern "C" void kernel_launch(void* const* d_in, const int* in_sizes, int n_in,
                              void* d_out, int out_size, void* d_ws, size_t ws_size,
                              hipStream_t stream) {
    const float* qkv    = (const float*)d_in[0];
    const float* sim    = (const float*)d_in[1];
    const float* proj_w = (const float*)d_in[2];
    const float* proj_b = (const float*)d_in[3];
    const float* lscale = (const float*)d_in[4];
    float* out = (float*)d_out;

    char* ws = (char*)d_ws;
    int* keys   = (int*)(ws);
    int* dest   = (int*)(ws + 524288);
    int* sidx   = (int*)(ws + 1048576);
    int* counts = (int*)(ws + 1572864);
    unsigned short* oattn = (unsigned short*)(ws + 1703936);

    argmax_kernel<<<32768, 256, 0, stream>>>(sim, keys);
    hist_kernel<<<B_ * NTILES_, 256, 0, stream>>>(keys, counts);
    scan_kernel<<<B_, 256, 0, stream>>>(counts);
    rank_kernel<<<B_ * NTILES_, 256, 0, stream>>>(keys, counts, sidx, dest);
    attn_kernel<<<B_ * NG_ * NH_, 256, 0, stream>>>(qkv, lscale, sidx, oattn);
    proj_kernel<<<dim3((B_ * N_) / 64, 2), 256, 0, stream>>>(oattn, dest, proj_w, proj_b, out);
}

// Round 3
// 247.348 us; speedup vs baseline: 2.1128x; 1.4502x over previous
//
#include <hip/hip_runtime.h>

#define B_  2
#define N_  65536
#define C_  192
#define NH_ 4
#define HD_ 48
#define GS_ 128
#define NG_ 512
#define NTILES_ 256   // per batch, tile = 256 tokens

typedef __attribute__((ext_vector_type(8))) short short8;
typedef __attribute__((ext_vector_type(4))) float f32x4;

__device__ __forceinline__ unsigned short f2bf(float f) {
    unsigned u = __float_as_uint(f);
    unsigned r = (u + 0x7FFFu + ((u >> 16) & 1u)) >> 16;
    return (unsigned short)r;
}
__device__ __forceinline__ float bf2f(unsigned short s) {
    return __uint_as_float(((unsigned)s) << 16);
}

// ---------------- K1: per-token argmax over 64 sim categories ----------------
__global__ __launch_bounds__(256) void argmax_kernel(const float* __restrict__ sim,
                                                     int* __restrict__ keys) {
    int lane  = threadIdx.x & 63;
    int token = blockIdx.x * 4 + (threadIdx.x >> 6);
    float v = sim[(size_t)token * 64 + lane];
    int idx = lane;
    #pragma unroll
    for (int m = 1; m < 64; m <<= 1) {
        float ov = __shfl_xor(v, m);
        int   oi = __shfl_xor(idx, m);
        if (ov > v || (ov == v && oi < idx)) { v = ov; idx = oi; }
    }
    if (lane == 0) keys[token] = idx;
}

// ---------------- K2: per-tile histogram (tile = 256 tokens) ----------------
__global__ __launch_bounds__(256) void hist_kernel(const int* __restrict__ keys,
                                                   int* __restrict__ counts) {
    __shared__ int hcnt[64];
    int tid  = threadIdx.x;
    int tile = blockIdx.x & (NTILES_ - 1);
    int bz   = blockIdx.x >> 8;
    if (tid < 64) hcnt[tid] = 0;
    __syncthreads();
    int k = keys[bz * N_ + tile * 256 + tid];
    atomicAdd(&hcnt[k], 1);
    __syncthreads();
    if (tid < 64) counts[(bz * NTILES_ + tile) * 64 + tid] = hcnt[tid];
}

// ---------------- K3: two-level scan, 256 threads (64 keys x 4 quarters) -----
__global__ __launch_bounds__(256) void scan_kernel(int* __restrict__ counts) {
    __shared__ int qsum[4][64];
    __shared__ int kbase[64];
    int bz = blockIdx.x;
    int k  = threadIdx.x & 63;
    int qt = threadIdx.x >> 6;
    int base_idx = (bz * NTILES_) * 64 + k;

    int sum = 0;
    #pragma unroll 8
    for (int t = qt * 64; t < qt * 64 + 64; ++t) sum += counts[base_idx + t * 64];
    qsum[qt][k] = sum;
    __syncthreads();

    if (qt == 0) {
        int tot = qsum[0][k] + qsum[1][k] + qsum[2][k] + qsum[3][k];
        int incl = tot;
        #pragma unroll
        for (int off = 1; off < 64; off <<= 1) {
            int v = __shfl_up(incl, off);
            if (k >= off) incl += v;
        }
        kbase[k] = incl - tot;   // exclusive prefix over keys
    }
    __syncthreads();

    int run = kbase[k];
    for (int q2 = 0; q2 < qt; ++q2) run += qsum[q2][k];
    #pragma unroll 8
    for (int t = qt * 64; t < qt * 64 + 64; ++t) {
        int idx = base_idx + t * 64;
        int c = counts[idx];
        counts[idx] = run;
        run += c;
    }
}

// ---------------- K4: stable in-tile rank via match-any ballot ---------------
__global__ __launch_bounds__(256) void rank_kernel(const int* __restrict__ keys,
                                                   const int* __restrict__ counts,
                                                   int* __restrict__ sidx,
                                                   int* __restrict__ dest) {
    __shared__ int whist[4 * 64];
    int tid  = threadIdx.x;
    int tile = blockIdx.x & (NTILES_ - 1);
    int bz   = blockIdx.x >> 8;
    whist[tid] = 0;
    __syncthreads();

    int tok = tile * 256 + tid;
    int key = keys[bz * N_ + tok];
    int w = tid >> 6, lane = tid & 63;

    unsigned long long mask = ~0ull;
    #pragma unroll
    for (int b = 0; b < 6; ++b) {
        unsigned long long bb = __ballot((key >> b) & 1);
        mask &= ((key >> b) & 1) ? bb : ~bb;
    }
    unsigned long long lt = (lane == 0) ? 0ull : (~0ull >> (64 - lane));
    int rank = __popcll(mask & lt);
    if (rank == 0) whist[w * 64 + key] = __popcll(mask);
    __syncthreads();

    int base = counts[(bz * NTILES_ + tile) * 64 + key];
    for (int w2 = 0; w2 < w; ++w2) base += whist[w2 * 64 + key];
    int pos = base + rank;
    sidx[bz * N_ + pos] = tok;
    dest[bz * N_ + tok] = pos;
}

// ---------------- K5: MFMA grouped attention, one block per (b, group, head) -
// Split-bf16 QK^T: S = Qh*Kh + Qh*Kl + Ql*Kh via concat-144 K-dim
// [Qh|Qh|Ql] x [Kh|Kl|Kh], 5 k-steps of 16x16x32 (last step zero-padded in
// registers). fp32 softmax in C-layout registers. P bf16 -> LDS (over K'),
// PV via bf16 MFMA with transposed V tile.
__global__ __launch_bounds__(256) void attn_kernel(const float* __restrict__ qkv,
                                                   const float* __restrict__ lscale,
                                                   const int* __restrict__ sort_idx,
                                                   unsigned short* __restrict__ oattn) {
    __shared__ unsigned short kp[128 * 152];   // K' [128][152]; later P [128][136]
    __shared__ unsigned short vt[48 * 136];    // V transposed [48][136]
    __shared__ int sidx_s[128];

    int x  = blockIdx.x;
    int h  = x & 3;
    int g  = (x >> 2) & (NG_ - 1);
    int bz = x >> 11;
    int tid = threadIdx.x;

    if (tid < 128) sidx_s[tid] = sort_idx[bz * N_ + g * GS_ + tid];
    __syncthreads();

    // ---- stage K' (hi|lo|hi concat) and Vt (transposed bf16) ----
    {
        int i = tid >> 1, part = tid & 1;
        size_t rb = (size_t)(bz * N_ + sidx_s[i]) * 576 + (part ? 384 : 192) + h * 48;
        const float4* src = (const float4*)(qkv + rb);
        if (part == 0) {
            unsigned hp[24], lp[24];
            #pragma unroll
            for (int m = 0; m < 12; ++m) {
                float4 f = src[m];
                float fv[4] = {f.x, f.y, f.z, f.w};
                #pragma unroll
                for (int j2 = 0; j2 < 2; ++j2) {
                    unsigned short h0 = f2bf(fv[2 * j2]);
                    unsigned short h1 = f2bf(fv[2 * j2 + 1]);
                    unsigned short l0 = f2bf(fv[2 * j2] - bf2f(h0));
                    unsigned short l1 = f2bf(fv[2 * j2 + 1] - bf2f(h1));
                    hp[m * 2 + j2] = (unsigned)h0 | ((unsigned)h1 << 16);
                    lp[m * 2 + j2] = (unsigned)l0 | ((unsigned)l1 << 16);
                }
            }
            uint4* kw = (uint4*)(kp + (size_t)i * 152);
            #pragma unroll
            for (int m = 0; m < 6; ++m) {
                kw[m]      = make_uint4(hp[4*m], hp[4*m+1], hp[4*m+2], hp[4*m+3]); // Kh @ 0
                kw[m + 6]  = make_uint4(lp[4*m], lp[4*m+1], lp[4*m+2], lp[4*m+3]); // Kl @ 48
                kw[m + 12] = make_uint4(hp[4*m], hp[4*m+1], hp[4*m+2], hp[4*m+3]); // Kh @ 96
            }
        } else {
            #pragma unroll
            for (int m = 0; m < 12; ++m) {
                float4 f = src[m];
                vt[(m * 4 + 0) * 136 + i] = f2bf(f.x);
                vt[(m * 4 + 1) * 136 + i] = f2bf(f.y);
                vt[(m * 4 + 2) * 136 + i] = f2bf(f.z);
                vt[(m * 4 + 3) * 136 + i] = f2bf(f.w);
            }
        }
    }

    float scale = __expf(fminf(lscale[0], 4.60517019f));
    int lane = tid & 63, wid = tid >> 6;
    int lr = lane & 15, lg = lane >> 4;
    int qt0 = wid * 2, qt1 = wid * 2 + 1;
    size_t qg0 = (size_t)(bz * N_ + sidx_s[qt0 * 16 + lr]) * 576 + h * 48;
    size_t qg1 = (size_t)(bz * N_ + sidx_s[qt1 * 16 + lr]) * 576 + h * 48;
    __syncthreads();

    // ---- QK^T ----
    f32x4 acc0[8], acc1[8];
    #pragma unroll
    for (int kt = 0; kt < 8; ++kt) { acc0[kt] = (f32x4)0.f; acc1[kt] = (f32x4)0.f; }

    int chunk = lg;  // chunk = s*4 + lg
    #pragma unroll
    for (int s = 0; s < 5; ++s, chunk += 4) {
        short8 a0 = (short8)0, a1 = (short8)0;
        if (chunk < 18) {
            int sec  = chunk / 6;               // 0,1 -> hi ; 2 -> lo
            int dim8 = (chunk - sec * 6) * 8;
            const float4* p0 = (const float4*)(qkv + qg0 + dim8);
            const float4* p1 = (const float4*)(qkv + qg1 + dim8);
            float4 f0a = p0[0], f0b = p0[1], f1a = p1[0], f1b = p1[1];
            float fv0[8] = {f0a.x, f0a.y, f0a.z, f0a.w, f0b.x, f0b.y, f0b.z, f0b.w};
            float fv1[8] = {f1a.x, f1a.y, f1a.z, f1a.w, f1b.x, f1b.y, f1b.z, f1b.w};
            #pragma unroll
            for (int j = 0; j < 8; ++j) {
                unsigned short h0 = f2bf(fv0[j]);
                unsigned short h1 = f2bf(fv1[j]);
                a0[j] = (sec == 2) ? (short)f2bf(fv0[j] - bf2f(h0)) : (short)h0;
                a1[j] = (sec == 2) ? (short)f2bf(fv1[j] - bf2f(h1)) : (short)h1;
            }
        }
        #pragma unroll
        for (int kt = 0; kt < 8; ++kt) {
            short8 b = (short8)0;
            if (chunk < 18)
                b = *(const short8*)(kp + (size_t)(kt * 16 + lr) * 152 + chunk * 8);
            acc0[kt] = __builtin_amdgcn_mfma_f32_16x16x32_bf16(a0, b, acc0[kt], 0, 0, 0);
            acc1[kt] = __builtin_amdgcn_mfma_f32_16x16x32_bf16(a1, b, acc1[kt], 0, 0, 0);
        }
    }

    // ---- softmax (rows = lg*4+r, cols = kt*16+lr) ----
    float inv0[4], inv1[4];
    {
        float mx0[4], mx1[4];
        #pragma unroll
        for (int r = 0; r < 4; ++r) { mx0[r] = -1e30f; mx1[r] = -1e30f; }
        #pragma unroll
        for (int kt = 0; kt < 8; ++kt)
            #pragma unroll
            for (int r = 0; r < 4; ++r) {
                acc0[kt][r] *= scale; acc1[kt][r] *= scale;
                mx0[r] = fmaxf(mx0[r], acc0[kt][r]);
                mx1[r] = fmaxf(mx1[r], acc1[kt][r]);
            }
        #pragma unroll
        for (int m = 1; m < 16; m <<= 1)
            #pragma unroll
            for (int r = 0; r < 4; ++r) {
                mx0[r] = fmaxf(mx0[r], __shfl_xor(mx0[r], m));
                mx1[r] = fmaxf(mx1[r], __shfl_xor(mx1[r], m));
            }
        float sm0[4] = {0.f, 0.f, 0.f, 0.f}, sm1[4] = {0.f, 0.f, 0.f, 0.f};
        #pragma unroll
        for (int kt = 0; kt < 8; ++kt)
            #pragma unroll
            for (int r = 0; r < 4; ++r) {
                float e0 = __expf(acc0[kt][r] - mx0[r]);
                float e1 = __expf(acc1[kt][r] - mx1[r]);
                acc0[kt][r] = e0; acc1[kt][r] = e1;
                sm0[r] += e0; sm1[r] += e1;
            }
        #pragma unroll
        for (int m = 1; m < 16; m <<= 1)
            #pragma unroll
            for (int r = 0; r < 4; ++r) {
                sm0[r] += __shfl_xor(sm0[r], m);
                sm1[r] += __shfl_xor(sm1[r], m);
            }
        #pragma unroll
        for (int r = 0; r < 4; ++r) { inv0[r] = 1.f / sm0[r]; inv1[r] = 1.f / sm1[r]; }
    }

    __syncthreads();   // all K' reads complete before P overwrites it

    // ---- write P (bf16, unnormalized) over K' region ----
    #pragma unroll
    for (int kt = 0; kt < 8; ++kt)
        #pragma unroll
        for (int r = 0; r < 4; ++r) {
            kp[(size_t)(qt0 * 16 + lg * 4 + r) * 136 + kt * 16 + lr] = f2bf(acc0[kt][r]);
            kp[(size_t)(qt1 * 16 + lg * 4 + r) * 136 + kt * 16 + lr] = f2bf(acc1[kt][r]);
        }
    __syncthreads();

    // ---- PV ----
    f32x4 o0[3], o1[3];
    #pragma unroll
    for (int dt = 0; dt < 3; ++dt) { o0[dt] = (f32x4)0.f; o1[dt] = (f32x4)0.f; }
    #pragma unroll
    for (int ks = 0; ks < 4; ++ks) {
        short8 a0 = *(const short8*)(kp + (size_t)(qt0 * 16 + lr) * 136 + ks * 32 + lg * 8);
        short8 a1 = *(const short8*)(kp + (size_t)(qt1 * 16 + lr) * 136 + ks * 32 + lg * 8);
        #pragma unroll
        for (int dt = 0; dt < 3; ++dt) {
            short8 bv = *(const short8*)(vt + (size_t)(dt * 16 + lr) * 136 + ks * 32 + lg * 8);
            o0[dt] = __builtin_amdgcn_mfma_f32_16x16x32_bf16(a0, bv, o0[dt], 0, 0, 0);
            o1[dt] = __builtin_amdgcn_mfma_f32_16x16x32_bf16(a1, bv, o1[dt], 0, 0, 0);
        }
    }

    // ---- store (normalize by row sums) ----
    #pragma unroll
    for (int dt = 0; dt < 3; ++dt)
        #pragma unroll
        for (int r = 0; r < 4; ++r) {
            int row0 = qt0 * 16 + lg * 4 + r;
            int row1 = qt1 * 16 + lg * 4 + r;
            oattn[(size_t)(bz * N_ + g * GS_ + row0) * C_ + h * HD_ + dt * 16 + lr] =
                f2bf(o0[dt][r] * inv0[r]);
            oattn[(size_t)(bz * N_ + g * GS_ + row1) * C_ + h * HD_ + dt * 16 + lr] =
                f2bf(o1[dt][r] * inv1[r]);
        }
}

// ---------------- K6a: convert W (192x192 fp32) to bf16 ----------------------
__global__ __launch_bounds__(256) void wconv_kernel(const float* __restrict__ W,
                                                    unsigned short* __restrict__ wbf) {
    int i = blockIdx.x * 256 + threadIdx.x;   // handles 4 elements
    float4 f = ((const float4*)W)[i];
    uint2 p;
    p.x = (unsigned)f2bf(f.x) | ((unsigned)f2bf(f.y) << 16);
    p.y = (unsigned)f2bf(f.z) | ((unsigned)f2bf(f.w) << 16);
    ((uint2*)wbf)[i] = p;
}

// ---------------- K6b: unshuffle + x @ W^T + b via MFMA ----------------------
// 128 rows x 192 cols per block, 4 waves. x fragments gathered per-lane from
// global (each row consumed exactly once -> no LDS staging); W fragments from
// global (identical addresses across blocks -> L2 broadcast).
__global__ __launch_bounds__(256) void proj2_kernel(const unsigned short* __restrict__ oattn,
                                                    const int* __restrict__ dest,
                                                    const unsigned short* __restrict__ wbf,
                                                    const float* __restrict__ bias,
                                                    float* __restrict__ out) {
    __shared__ int mpos[128];
    int tid = threadIdx.x;
    int m0  = blockIdx.x * 128;

    if (tid < 128) {
        int m = m0 + tid;
        int bz = m >> 16;
        mpos[tid] = bz * N_ + dest[m];
    }
    __syncthreads();

    int lane = tid & 63, wid = tid >> 6;
    int lr = lane & 15, lg = lane >> 4;
    int mt0 = wid * 2, mt1 = wid * 2 + 1;

    const unsigned short* xr0 = oattn + (size_t)mpos[mt0 * 16 + lr] * C_ + lg * 8;
    const unsigned short* xr1 = oattn + (size_t)mpos[mt1 * 16 + lr] * C_ + lg * 8;
    const unsigned short* wr  = wbf + (size_t)lr * C_ + lg * 8;

    f32x4 acc[2][12];
    #pragma unroll
    for (int mt = 0; mt < 2; ++mt)
        #pragma unroll
        for (int jt = 0; jt < 12; ++jt) acc[mt][jt] = (f32x4)0.f;

    #pragma unroll
    for (int ks = 0; ks < 6; ++ks) {
        short8 a0 = *(const short8*)(xr0 + ks * 32);
        short8 a1 = *(const short8*)(xr1 + ks * 32);
        #pragma unroll
        for (int jt = 0; jt < 12; ++jt) {
            short8 b = *(const short8*)(wr + (size_t)jt * 16 * C_ + ks * 32);
            acc[0][jt] = __builtin_amdgcn_mfma_f32_16x16x32_bf16(a0, b, acc[0][jt], 0, 0, 0);
            acc[1][jt] = __builtin_amdgcn_mfma_f32_16x16x32_bf16(a1, b, acc[1][jt], 0, 0, 0);
        }
    }

    #pragma unroll
    for (int jt = 0; jt < 12; ++jt) {
        int j = jt * 16 + lr;
        float bj = bias[j];
        #pragma unroll
        for (int r = 0; r < 4; ++r) {
            int row0 = m0 + mt0 * 16 + lg * 4 + r;
            int row1 = m0 + mt1 * 16 + lg * 4 + r;
            out[(size_t)row0 * C_ + j] = acc[0][jt][r] + bj;
            out[(size_t)row1 * C_ + j] = acc[1][jt][r] + bj;
        }
    }
}

extern "C" void kernel_launch(void* const* d_in, const int* in_sizes, int n_in,
                              void* d_out, int out_size, void* d_ws, size_t ws_size,
                              hipStream_t stream) {
    const float* qkv    = (const float*)d_in[0];
    const float* sim    = (const float*)d_in[1];
    const float* proj_w = (const float*)d_in[2];
    const float* proj_b = (const float*)d_in[3];
    const float* lscale = (const float*)d_in[4];
    float* out = (float*)d_out;

    char* ws = (char*)d_ws;
    int* keys   = (int*)(ws);
    int* dest   = (int*)(ws + 524288);
    int* sidx   = (int*)(ws + 1048576);
    int* counts = (int*)(ws + 1572864);
    unsigned short* oattn = (unsigned short*)(ws + 1703936);          // 50331648 B
    unsigned short* wbf   = (unsigned short*)(ws + 1703936 + 50331648); // 73728 B

    argmax_kernel<<<32768, 256, 0, stream>>>(sim, keys);
    hist_kernel<<<B_ * NTILES_, 256, 0, stream>>>(keys, counts);
    scan_kernel<<<B_, 256, 0, stream>>>(counts);
    rank_kernel<<<B_ * NTILES_, 256, 0, stream>>>(keys, counts, sidx, dest);
    wconv_kernel<<<36, 256, 0, stream>>>(proj_w, wbf);
    attn_kernel<<<B_ * NG_ * NH_, 256, 0, stream>>>(qkv, lscale, sidx, oattn);
    proj2_kernel<<<(B_ * N_) / 128, 256, 0, stream>>>(oattn, dest, wbf, proj_b, out);
}

// Round 4
// 216.444 us; speedup vs baseline: 2.4145x; 1.1428x over previous
//
#include <hip/hip_runtime.h>

#define B_  2
#define N_  65536
#define C_  192
#define NH_ 4
#define HD_ 48
#define GS_ 128
#define NG_ 512
#define NTILES_ 256   // per batch, tile = 256 tokens

typedef __attribute__((ext_vector_type(8))) short short8;
typedef __attribute__((ext_vector_type(4))) float f32x4;

__device__ __forceinline__ unsigned short f2bf(float f) {
    unsigned u = __float_as_uint(f);
    unsigned r = (u + 0x7FFFu + ((u >> 16) & 1u)) >> 16;
    return (unsigned short)r;
}
__device__ __forceinline__ float bf2f(unsigned short s) {
    return __uint_as_float(((unsigned)s) << 16);
}
// packed RNE f32x2 -> bf16x2 (low short = a, high short = b)
__device__ __forceinline__ unsigned cvt_pk(float a, float b) {
    unsigned r;
    asm("v_cvt_pk_bf16_f32 %0, %1, %2" : "=v"(r) : "v"(a), "v"(b));
    return r;
}

// ---------------- K1: per-token argmax over 64 sim categories ----------------
__global__ __launch_bounds__(256) void argmax_kernel(const float* __restrict__ sim,
                                                     int* __restrict__ keys) {
    int lane  = threadIdx.x & 63;
    int token = blockIdx.x * 4 + (threadIdx.x >> 6);
    float v = sim[(size_t)token * 64 + lane];
    int idx = lane;
    #pragma unroll
    for (int m = 1; m < 64; m <<= 1) {
        float ov = __shfl_xor(v, m);
        int   oi = __shfl_xor(idx, m);
        if (ov > v || (ov == v && oi < idx)) { v = ov; idx = oi; }
    }
    if (lane == 0) keys[token] = idx;
}

// ---------------- K2: per-tile histogram (tile = 256 tokens) ----------------
__global__ __launch_bounds__(256) void hist_kernel(const int* __restrict__ keys,
                                                   int* __restrict__ counts) {
    __shared__ int hcnt[64];
    int tid  = threadIdx.x;
    int tile = blockIdx.x & (NTILES_ - 1);
    int bz   = blockIdx.x >> 8;
    if (tid < 64) hcnt[tid] = 0;
    __syncthreads();
    int k = keys[bz * N_ + tile * 256 + tid];
    atomicAdd(&hcnt[k], 1);
    __syncthreads();
    if (tid < 64) counts[(bz * NTILES_ + tile) * 64 + tid] = hcnt[tid];
}

// ---------------- K3: two-level scan, 256 threads (64 keys x 4 quarters) -----
__global__ __launch_bounds__(256) void scan_kernel(int* __restrict__ counts) {
    __shared__ int qsum[4][64];
    __shared__ int kbase[64];
    int bz = blockIdx.x;
    int k  = threadIdx.x & 63;
    int qt = threadIdx.x >> 6;
    int base_idx = (bz * NTILES_) * 64 + k;

    int sum = 0;
    #pragma unroll 8
    for (int t = qt * 64; t < qt * 64 + 64; ++t) sum += counts[base_idx + t * 64];
    qsum[qt][k] = sum;
    __syncthreads();

    if (qt == 0) {
        int tot = qsum[0][k] + qsum[1][k] + qsum[2][k] + qsum[3][k];
        int incl = tot;
        #pragma unroll
        for (int off = 1; off < 64; off <<= 1) {
            int v = __shfl_up(incl, off);
            if (k >= off) incl += v;
        }
        kbase[k] = incl - tot;
    }
    __syncthreads();

    int run = kbase[k];
    for (int q2 = 0; q2 < qt; ++q2) run += qsum[q2][k];
    #pragma unroll 8
    for (int t = qt * 64; t < qt * 64 + 64; ++t) {
        int idx = base_idx + t * 64;
        int c = counts[idx];
        counts[idx] = run;
        run += c;
    }
}

// ---------------- K4: stable in-tile rank via match-any ballot ---------------
__global__ __launch_bounds__(256) void rank_kernel(const int* __restrict__ keys,
                                                   const int* __restrict__ counts,
                                                   int* __restrict__ sidx,
                                                   int* __restrict__ dest) {
    __shared__ int whist[4 * 64];
    int tid  = threadIdx.x;
    int tile = blockIdx.x & (NTILES_ - 1);
    int bz   = blockIdx.x >> 8;
    whist[tid] = 0;
    __syncthreads();

    int tok = tile * 256 + tid;
    int key = keys[bz * N_ + tok];
    int w = tid >> 6, lane = tid & 63;

    unsigned long long mask = ~0ull;
    #pragma unroll
    for (int b = 0; b < 6; ++b) {
        unsigned long long bb = __ballot((key >> b) & 1);
        mask &= ((key >> b) & 1) ? bb : ~bb;
    }
    unsigned long long lt = (lane == 0) ? 0ull : (~0ull >> (64 - lane));
    int rank = __popcll(mask & lt);
    if (rank == 0) whist[w * 64 + key] = __popcll(mask);
    __syncthreads();

    int base = counts[(bz * NTILES_ + tile) * 64 + key];
    for (int w2 = 0; w2 < w; ++w2) base += whist[w2 * 64 + key];
    int pos = base + rank;
    sidx[bz * N_ + pos] = tok;
    dest[bz * N_ + tok] = pos;
}

// ---------------- K5: MFMA grouped attention (latency-optimized) -------------
// K' = [Kh|Kl] (stride 104). QK^T = pass1 [Qh|Ql]x[Kh|Kh] (3 steps) +
// pass2 Qh x Kl (2 steps, zero-padded tail). Q hoisted to registers. P[128][136]
// overlays K' after one barrier; P rows are wave-private -> no second barrier.
#define KP_STRIDE 104
#define P_STRIDE  136
#define VT_STRIDE 136
#define SM_VT   34816              // max(128*104*2, 128*136*2)
#define SM_SIDX (SM_VT + 48*VT_STRIDE*2)
#define SM_SIZE (SM_SIDX + 512)

__global__ __launch_bounds__(256, 3) void attn_kernel(const float* __restrict__ qkv,
                                                      const float* __restrict__ lscale,
                                                      const int* __restrict__ sort_idx,
                                                      unsigned short* __restrict__ oattn) {
    __shared__ __align__(16) char smem[SM_SIZE];
    unsigned short* kp = (unsigned short*)smem;          // K' [128][104]; later P [128][136]
    unsigned short* vt = (unsigned short*)(smem + SM_VT);// V^T [48][136]
    int* sidx_s = (int*)(smem + SM_SIDX);

    int x  = blockIdx.x;
    int h  = x & 3;
    int g  = (x >> 2) & (NG_ - 1);
    int bz = x >> 11;
    int tid = threadIdx.x;

    if (tid < 128) sidx_s[tid] = sort_idx[bz * N_ + g * GS_ + tid];
    __syncthreads();

    int lane = tid & 63, wid = tid >> 6;
    int lr = lane & 15, lg = lane >> 4;
    int qt0 = wid * 2, qt1 = qt0 + 1;
    float scale = __expf(fminf(lscale[0], 4.60517019f));

    // ---- hoisted Q gather loads: 3 ranges x 2 float4 x 2 rows ----
    int r0s = lg * 8;
    int r1s = 16 + lg * 8;
    int r2s = (lg < 2) ? 32 + lg * 8 : (lg - 2) * 8;
    const float* q0p = qkv + (size_t)(bz * N_ + sidx_s[qt0 * 16 + lr]) * 576 + h * 48;
    const float* q1p = qkv + (size_t)(bz * N_ + sidx_s[qt1 * 16 + lr]) * 576 + h * 48;
    float4 qA0 = *(const float4*)(q0p + r0s), qA1 = *(const float4*)(q0p + r0s + 4);
    float4 qB0 = *(const float4*)(q0p + r1s), qB1 = *(const float4*)(q0p + r1s + 4);
    float4 qC0 = *(const float4*)(q0p + r2s), qC1 = *(const float4*)(q0p + r2s + 4);
    float4 pA0 = *(const float4*)(q1p + r0s), pA1 = *(const float4*)(q1p + r0s + 4);
    float4 pB0 = *(const float4*)(q1p + r1s), pB1 = *(const float4*)(q1p + r1s + 4);
    float4 pC0 = *(const float4*)(q1p + r2s), pC1 = *(const float4*)(q1p + r2s + 4);

    // ---- stage K (flat coalesced): 1536 float4 over 256 threads ----
    #pragma unroll
    for (int it = 0; it < 6; ++it) {
        int f = it * 256 + tid;
        int row = f / 12, piece = f - row * 12;
        float4 kf = *(const float4*)(qkv + (size_t)(bz * N_ + sidx_s[row]) * 576 + 192 + h * 48 + piece * 4);
        unsigned h01 = cvt_pk(kf.x, kf.y), h23 = cvt_pk(kf.z, kf.w);
        float hx = __uint_as_float(h01 << 16), hy = __uint_as_float(h01 & 0xFFFF0000u);
        float hz = __uint_as_float(h23 << 16), hw = __uint_as_float(h23 & 0xFFFF0000u);
        unsigned l01 = cvt_pk(kf.x - hx, kf.y - hy), l23 = cvt_pk(kf.z - hz, kf.w - hw);
        *(uint2*)(kp + row * KP_STRIDE + piece * 4)      = make_uint2(h01, h23);
        *(uint2*)(kp + row * KP_STRIDE + 48 + piece * 4) = make_uint2(l01, l23);
    }
    // ---- stage V^T (flat coalesced) ----
    #pragma unroll
    for (int it = 0; it < 6; ++it) {
        int f = it * 256 + tid;
        int row = f / 12, piece = f - row * 12;
        float4 vf = *(const float4*)(qkv + (size_t)(bz * N_ + sidx_s[row]) * 576 + 384 + h * 48 + piece * 4);
        int d = piece * 4;
        vt[(d + 0) * VT_STRIDE + row] = f2bf(vf.x);
        vt[(d + 1) * VT_STRIDE + row] = f2bf(vf.y);
        vt[(d + 2) * VT_STRIDE + row] = f2bf(vf.z);
        vt[(d + 3) * VT_STRIDE + row] = f2bf(vf.w);
    }

    // ---- convert Q (pre-scaled) to a-frags: af[s][w] dwords ----
    unsigned af0[5][4], af1[5][4];
    {
        float a0[8] = {qA0.x,qA0.y,qA0.z,qA0.w,qA1.x,qA1.y,qA1.z,qA1.w};
        float b0[8] = {qB0.x,qB0.y,qB0.z,qB0.w,qB1.x,qB1.y,qB1.z,qB1.w};
        float c0[8] = {qC0.x,qC0.y,qC0.z,qC0.w,qC1.x,qC1.y,qC1.z,qC1.w};
        float a1[8] = {pA0.x,pA0.y,pA0.z,pA0.w,pA1.x,pA1.y,pA1.z,pA1.w};
        float b1[8] = {pB0.x,pB0.y,pB0.z,pB0.w,pB1.x,pB1.y,pB1.z,pB1.w};
        float c1[8] = {pC0.x,pC0.y,pC0.z,pC0.w,pC1.x,pC1.y,pC1.z,pC1.w};
        #pragma unroll
        for (int j = 0; j < 8; ++j) {
            a0[j] *= scale; b0[j] *= scale; c0[j] *= scale;
            a1[j] *= scale; b1[j] *= scale; c1[j] *= scale;
        }
        #pragma unroll
        for (int w = 0; w < 4; ++w) {
            // F0 = hi(r0) : steps 0 and 3
            af0[0][w] = cvt_pk(a0[2*w], a0[2*w+1]);
            af1[0][w] = cvt_pk(a1[2*w], a1[2*w+1]);
            af0[3][w] = af0[0][w];
            af1[3][w] = af1[0][w];
            // F2 = lo(r1) : step 2
            {
                unsigned t0 = cvt_pk(b0[2*w], b0[2*w+1]);
                float hx = __uint_as_float(t0 << 16), hy = __uint_as_float(t0 & 0xFFFF0000u);
                af0[2][w] = cvt_pk(b0[2*w] - hx, b0[2*w+1] - hy);
                unsigned t1 = cvt_pk(b1[2*w], b1[2*w+1]);
                float ix = __uint_as_float(t1 << 16), iy = __uint_as_float(t1 & 0xFFFF0000u);
                af1[2][w] = cvt_pk(b1[2*w] - ix, b1[2*w+1] - iy);
            }
            // F1 = lg<2 ? hi(r2) : lo(r2) : step 1; step 4 = lg<2 ? F1 : 0
            if (lg < 2) {
                af0[1][w] = cvt_pk(c0[2*w], c0[2*w+1]);
                af1[1][w] = cvt_pk(c1[2*w], c1[2*w+1]);
                af0[4][w] = af0[1][w];
                af1[4][w] = af1[1][w];
            } else {
                unsigned t0 = cvt_pk(c0[2*w], c0[2*w+1]);
                float hx = __uint_as_float(t0 << 16), hy = __uint_as_float(t0 & 0xFFFF0000u);
                af0[1][w] = cvt_pk(c0[2*w] - hx, c0[2*w+1] - hy);
                unsigned t1 = cvt_pk(c1[2*w], c1[2*w+1]);
                float ix = __uint_as_float(t1 << 16), iy = __uint_as_float(t1 & 0xFFFF0000u);
                af1[1][w] = cvt_pk(c1[2*w] - ix, c1[2*w+1] - iy);
                af0[4][w] = 0; af1[4][w] = 0;
            }
        }
    }
    __syncthreads();

    // ---- QK^T: 5 steps, b-frag offsets into [Kh(0..47)|Kl(48..95)] ----
    const int boffs[5] = { lg * 8, (32 + lg * 8) % 48, 16 + lg * 8,
                           48 + lg * 8, (lg < 2) ? 80 + lg * 8 : 48 };
    f32x4 acc0[8], acc1[8];
    #pragma unroll
    for (int kt = 0; kt < 8; ++kt) { acc0[kt] = (f32x4)0.f; acc1[kt] = (f32x4)0.f; }

    #pragma unroll
    for (int s = 0; s < 5; ++s) {
        union { short8 v; unsigned u[4]; } ua, ub;
        #pragma unroll
        for (int w = 0; w < 4; ++w) { ua.u[w] = af0[s][w]; ub.u[w] = af1[s][w]; }
        short8 a0 = ua.v, a1 = ub.v;
        #pragma unroll
        for (int kt = 0; kt < 8; ++kt) {
            short8 b = *(const short8*)(kp + (size_t)(kt * 16 + lr) * KP_STRIDE + boffs[s]);
            acc0[kt] = __builtin_amdgcn_mfma_f32_16x16x32_bf16(a0, b, acc0[kt], 0, 0, 0);
            acc1[kt] = __builtin_amdgcn_mfma_f32_16x16x32_bf16(a1, b, acc1[kt], 0, 0, 0);
        }
    }

    // ---- softmax (rows = lg*4+r, cols = kt*16+lr); scale already folded ----
    float inv0[4], inv1[4];
    {
        float mx0[4], mx1[4];
        #pragma unroll
        for (int r = 0; r < 4; ++r) { mx0[r] = -1e30f; mx1[r] = -1e30f; }
        #pragma unroll
        for (int kt = 0; kt < 8; ++kt)
            #pragma unroll
            for (int r = 0; r < 4; ++r) {
                mx0[r] = fmaxf(mx0[r], acc0[kt][r]);
                mx1[r] = fmaxf(mx1[r], acc1[kt][r]);
            }
        #pragma unroll
        for (int m = 1; m < 16; m <<= 1)
            #pragma unroll
            for (int r = 0; r < 4; ++r) {
                mx0[r] = fmaxf(mx0[r], __shfl_xor(mx0[r], m));
                mx1[r] = fmaxf(mx1[r], __shfl_xor(mx1[r], m));
            }
        float sm0[4] = {0.f,0.f,0.f,0.f}, sm1[4] = {0.f,0.f,0.f,0.f};
        #pragma unroll
        for (int kt = 0; kt < 8; ++kt)
            #pragma unroll
            for (int r = 0; r < 4; ++r) {
                float e0 = __expf(acc0[kt][r] - mx0[r]);
                float e1 = __expf(acc1[kt][r] - mx1[r]);
                acc0[kt][r] = e0; acc1[kt][r] = e1;
                sm0[r] += e0; sm1[r] += e1;
            }
        #pragma unroll
        for (int m = 1; m < 16; m <<= 1)
            #pragma unroll
            for (int r = 0; r < 4; ++r) {
                sm0[r] += __shfl_xor(sm0[r], m);
                sm1[r] += __shfl_xor(sm1[r], m);
            }
        #pragma unroll
        for (int r = 0; r < 4; ++r) { inv0[r] = 1.f / sm0[r]; inv1[r] = 1.f / sm1[r]; }
    }

    __syncthreads();   // all waves done reading K' before P overwrites region

    // ---- write P (bf16, unnormalized) into own wave's rows; no barrier ----
    #pragma unroll
    for (int kt = 0; kt < 8; ++kt)
        #pragma unroll
        for (int r = 0; r < 4; ++r) {
            kp[(size_t)(qt0 * 16 + lg * 4 + r) * P_STRIDE + kt * 16 + lr] = (unsigned short)cvt_pk(acc0[kt][r], acc0[kt][r]);
            kp[(size_t)(qt1 * 16 + lg * 4 + r) * P_STRIDE + kt * 16 + lr] = (unsigned short)cvt_pk(acc1[kt][r], acc1[kt][r]);
        }

    // ---- PV (reads own wave's P rows + vt) ----
    f32x4 o0[3], o1[3];
    #pragma unroll
    for (int dt = 0; dt < 3; ++dt) { o0[dt] = (f32x4)0.f; o1[dt] = (f32x4)0.f; }
    #pragma unroll
    for (int ks = 0; ks < 4; ++ks) {
        short8 a0 = *(const short8*)(kp + (size_t)(qt0 * 16 + lr) * P_STRIDE + ks * 32 + lg * 8);
        short8 a1 = *(const short8*)(kp + (size_t)(qt1 * 16 + lr) * P_STRIDE + ks * 32 + lg * 8);
        #pragma unroll
        for (int dt = 0; dt < 3; ++dt) {
            short8 bv = *(const short8*)(vt + (size_t)(dt * 16 + lr) * VT_STRIDE + ks * 32 + lg * 8);
            o0[dt] = __builtin_amdgcn_mfma_f32_16x16x32_bf16(a0, bv, o0[dt], 0, 0, 0);
            o1[dt] = __builtin_amdgcn_mfma_f32_16x16x32_bf16(a1, bv, o1[dt], 0, 0, 0);
        }
    }

    // ---- store (normalize by row sums) ----
    #pragma unroll
    for (int dt = 0; dt < 3; ++dt)
        #pragma unroll
        for (int r = 0; r < 4; ++r) {
            int row0 = qt0 * 16 + lg * 4 + r;
            int row1 = qt1 * 16 + lg * 4 + r;
            oattn[(size_t)(bz * N_ + g * GS_ + row0) * C_ + h * HD_ + dt * 16 + lr] =
                f2bf(o0[dt][r] * inv0[r]);
            oattn[(size_t)(bz * N_ + g * GS_ + row1) * C_ + h * HD_ + dt * 16 + lr] =
                f2bf(o1[dt][r] * inv1[r]);
        }
}

// ---------------- K6a: convert W (192x192 fp32) to bf16 ----------------------
__global__ __launch_bounds__(256) void wconv_kernel(const float* __restrict__ W,
                                                    unsigned short* __restrict__ wbf) {
    int i = blockIdx.x * 256 + threadIdx.x;
    float4 f = ((const float4*)W)[i];
    uint2 p;
    p.x = (unsigned)f2bf(f.x) | ((unsigned)f2bf(f.y) << 16);
    p.y = (unsigned)f2bf(f.z) | ((unsigned)f2bf(f.w) << 16);
    ((uint2*)wbf)[i] = p;
}

// ---------------- K6b: unshuffle + x @ W^T + b via MFMA ----------------------
__global__ __launch_bounds__(256) void proj2_kernel(const unsigned short* __restrict__ oattn,
                                                    const int* __restrict__ dest,
                                                    const unsigned short* __restrict__ wbf,
                                                    const float* __restrict__ bias,
                                                    float* __restrict__ out) {
    __shared__ int mpos[128];
    int tid = threadIdx.x;
    int m0  = blockIdx.x * 128;

    if (tid < 128) {
        int m = m0 + tid;
        int bz = m >> 16;
        mpos[tid] = bz * N_ + dest[m];
    }
    __syncthreads();

    int lane = tid & 63, wid = tid >> 6;
    int lr = lane & 15, lg = lane >> 4;
    int mt0 = wid * 2, mt1 = wid * 2 + 1;

    const unsigned short* xr0 = oattn + (size_t)mpos[mt0 * 16 + lr] * C_ + lg * 8;
    const unsigned short* xr1 = oattn + (size_t)mpos[mt1 * 16 + lr] * C_ + lg * 8;
    const unsigned short* wr  = wbf + (size_t)lr * C_ + lg * 8;

    f32x4 acc[2][12];
    #pragma unroll
    for (int mt = 0; mt < 2; ++mt)
        #pragma unroll
        for (int jt = 0; jt < 12; ++jt) acc[mt][jt] = (f32x4)0.f;

    #pragma unroll
    for (int ks = 0; ks < 6; ++ks) {
        short8 a0 = *(const short8*)(xr0 + ks * 32);
        short8 a1 = *(const short8*)(xr1 + ks * 32);
        #pragma unroll
        for (int jt = 0; jt < 12; ++jt) {
            short8 b = *(const short8*)(wr + (size_t)jt * 16 * C_ + ks * 32);
            acc[0][jt] = __builtin_amdgcn_mfma_f32_16x16x32_bf16(a0, b, acc[0][jt], 0, 0, 0);
            acc[1][jt] = __builtin_amdgcn_mfma_f32_16x16x32_bf16(a1, b, acc[1][jt], 0, 0, 0);
        }
    }

    #pragma unroll
    for (int jt = 0; jt < 12; ++jt) {
        int j = jt * 16 + lr;
        float bj = bias[j];
        #pragma unroll
        for (int r = 0; r < 4; ++r) {
            int row0 = m0 + mt0 * 16 + lg * 4 + r;
            int row1 = m0 + mt1 * 16 + lg * 4 + r;
            out[(size_t)row0 * C_ + j] = acc[0][jt][r] + bj;
            out[(size_t)row1 * C_ + j] = acc[1][jt][r] + bj;
        }
    }
}

extern "C" void kernel_launch(void* const* d_in, const int* in_sizes, int n_in,
                              void* d_out, int out_size, void* d_ws, size_t ws_size,
                              hipStream_t stream) {
    const float* qkv    = (const float*)d_in[0];
    const float* sim    = (const float*)d_in[1];
    const float* proj_w = (const float*)d_in[2];
    const float* proj_b = (const float*)d_in[3];
    const float* lscale = (const float*)d_in[4];
    float* out = (float*)d_out;

    char* ws = (char*)d_ws;
    int* keys   = (int*)(ws);
    int* dest   = (int*)(ws + 524288);
    int* sidx   = (int*)(ws + 1048576);
    int* counts = (int*)(ws + 1572864);
    unsigned short* oattn = (unsigned short*)(ws + 1703936);            // 50331648 B
    unsigned short* wbf   = (unsigned short*)(ws + 1703936 + 50331648); // 73728 B

    argmax_kernel<<<32768, 256, 0, stream>>>(sim, keys);
    hist_kernel<<<B_ * NTILES_, 256, 0, stream>>>(keys, counts);
    scan_kernel<<<B_, 256, 0, stream>>>(counts);
    rank_kernel<<<B_ * NTILES_, 256, 0, stream>>>(keys, counts, sidx, dest);
    wconv_kernel<<<36, 256, 0, stream>>>(proj_w, wbf);
    attn_kernel<<<B_ * NG_ * NH_, 256, 0, stream>>>(qkv, lscale, sidx, oattn);
    proj2_kernel<<<(B_ * N_) / 128, 256, 0, stream>>>(oattn, dest, wbf, proj_b, out);
}